// Round 2
// baseline (117.552 us; speedup 1.0000x reference)
//
#include <hip/hip_runtime.h>
#include <math.h>

#define NROWS 2048
#define KDIM  20000
#define PDIM  32
#define NTILE 1250            // 20000 / 16 column tiles
#define RGRP  16              // row groups (2048 / 128)
#define CCHUNKS 64            // column chunks
#define MAINB (RGRP * CCHUNKS)  // 1024 main blocks
#define PRIORB 64
#define STATS_N (NROWS * 4)

typedef short bf16x8 __attribute__((ext_vector_type(8)));
typedef float f32x4  __attribute__((ext_vector_type(4)));

__device__ __forceinline__ short f2bf(float f) {
  unsigned u = __float_as_uint(f);
  u += 0x7FFF + ((u >> 16) & 1);          // RNE
  return (short)(u >> 16);
}

__device__ __forceinline__ float wredf(float v) {
#pragma unroll
  for (int o = 32; o > 0; o >>= 1) v += __shfl_down(v, o, 64);
  return v;
}
__device__ __forceinline__ double wredd(double v) {
#pragma unroll
  for (int o = 32; o > 0; o >>= 1) v += __shfl_down(v, o, 64);
  return v;
}

__global__ void init_ws_k(float* stats, double* acc) {
  int i = blockIdx.x * blockDim.x + threadIdx.x;
  if (i < STATS_N) stats[i] = 0.0f;
  if (i == 0) acc[0] = 0.0;
}

// blocks [0, MAINB): fused bf16-MFMA logits + multinomial stats.
// blocks [MAINB, MAINB+PRIORB): Gaussian prior term.
__global__ __launch_bounds__(256, 4) void mainprior_k(
    const float* __restrict__ X, const int* __restrict__ Y,
    const float* __restrict__ mu, const float* __restrict__ beta,
    const float* __restrict__ m0p, const float* __restrict__ s0p,
    float* __restrict__ stats, double* __restrict__ acc)
{
  __shared__ float lgt[128];
  __shared__ float red[4];
  const int tid = threadIdx.x;

  if (blockIdx.x >= MAINB) {
    // ---------------- prior blocks ----------------
    const int b = blockIdx.x - MAINB;
    const float m0 = m0p[0], s0 = s0p[0];
    const float inv2s2 = 0.5f / (s0 * s0);
    const float cnst = -0.5f * logf(6.283185307179586f * s0 * s0);
    const int total = KDIM + PDIM * KDIM;
    float fs = 0.0f;
    for (int i = b * 256 + tid; i < total; i += PRIORB * 256) {
      float v = (i < KDIM) ? mu[i] : beta[i - KDIM];
      float d = v - m0;
      fs += cnst - d * d * inv2s2;
    }
    fs = wredf(fs);
    if ((tid & 63) == 0) red[tid >> 6] = fs;
    __syncthreads();
    if (tid == 0) {
      double t = (double)red[0] + (double)red[1] + (double)red[2] + (double)red[3];
      atomicAdd(acc, t);
    }
    return;
  }

  // ---------------- main blocks ----------------
  const int brow  = blockIdx.x / CCHUNKS;   // 0..15
  const int chunk = blockIdx.x % CCHUNKS;   // 0..63
  const int wave = tid >> 6;
  const int lane = tid & 63;
  const int lg = lane >> 4;                 // lane group 0..3
  const int ln = lane & 15;                 // lane within group
  const int rowbase = brow * 128 + wave * 32;   // wave owns rows [rowbase, +32)

  if (tid < 128) lgt[tid] = lgammaf((float)tid + 1.0f);
  __syncthreads();

  // A fragments: X rows, bf16, held for the whole kernel.
  // mfma_f32_16x16x32_bf16 A layout: row = lane&15, k = (lane>>4)*8 + i
  bf16x8 a[2];
#pragma unroll
  for (int T = 0; T < 2; ++T) {
    const float* xp = X + (rowbase + T * 16 + ln) * PDIM + lg * 8;
    float4 x0 = *(const float4*)xp;
    float4 x1 = *(const float4*)(xp + 4);
    a[T][0] = f2bf(x0.x); a[T][1] = f2bf(x0.y);
    a[T][2] = f2bf(x0.z); a[T][3] = f2bf(x0.w);
    a[T][4] = f2bf(x1.x); a[T][5] = f2bf(x1.y);
    a[T][6] = f2bf(x1.z); a[T][7] = f2bf(x1.w);
  }

  // Per-row stats: slot s = T*4 + j holds row = rowbase + T*16 + lg*4 + j
  float S[8], SY[8], SYL[8], SLG[8];
#pragma unroll
  for (int s = 0; s < 8; ++s) { S[s] = 0.f; SY[s] = 0.f; SYL[s] = 0.f; SLG[s] = 0.f; }

  // B base: col = ln, k(p) = lg*8 + i  (B layout symmetric to A)
  const float* bbase = beta + (lg * 8) * KDIM + ln;
  int yoff[8];
#pragma unroll
  for (int T = 0; T < 2; ++T)
#pragma unroll
    for (int j = 0; j < 4; ++j)
      yoff[T * 4 + j] = (rowbase + T * 16 + lg * 4 + j) * KDIM + ln;

  for (int t = chunk; t < NTILE; t += CCHUNKS) {
    const int col0 = t * 16;

    // Y for this tile: 8 dwords/lane, 64B segments fully used
    int yv[8];
#pragma unroll
    for (int s = 0; s < 8; ++s) yv[s] = Y[yoff[s] + col0];

    // B fragment: 8 strided dwords (L2-resident beta)
    float bfv[8];
#pragma unroll
    for (int i = 0; i < 8; ++i) bfv[i] = bbase[i * KDIM + col0];

    const float muv = mu[col0 + ln];

    bf16x8 bv;
#pragma unroll
    for (int i = 0; i < 8; ++i) bv[i] = f2bf(bfv[i]);

#pragma unroll
    for (int T = 0; T < 2; ++T) {
      f32x4 c = { muv, muv, muv, muv };   // fold mu into the accumulator init
      c = __builtin_amdgcn_mfma_f32_16x16x32_bf16(a[T], bv, c, 0, 0, 0);
#pragma unroll
      for (int j = 0; j < 4; ++j) {
        const int s = T * 4 + j;
        const float logit = c[j];
        S[s] += __expf(logit);
        const float yf = (float)yv[s];
        SY[s]  += yf;
        SYL[s] += yf * logit;
        SLG[s] += lgt[yv[s]];
      }
    }
  }

  // Reduce across the 16 lanes of each lane-group (cols of the tile)
#pragma unroll
  for (int m = 1; m <= 8; m <<= 1) {
#pragma unroll
    for (int s = 0; s < 8; ++s) {
      S[s]   += __shfl_xor(S[s],   m, 64);
      SY[s]  += __shfl_xor(SY[s],  m, 64);
      SYL[s] += __shfl_xor(SYL[s], m, 64);
      SLG[s] += __shfl_xor(SLG[s], m, 64);
    }
  }
  if (ln == 0) {
#pragma unroll
    for (int T = 0; T < 2; ++T)
#pragma unroll
      for (int j = 0; j < 4; ++j) {
        const int s = T * 4 + j;
        const int row = rowbase + T * 16 + lg * 4 + j;
        atomicAdd(&stats[row * 4 + 0], S[s]);
        atomicAdd(&stats[row * 4 + 1], SY[s]);
        atomicAdd(&stats[row * 4 + 2], SYL[s]);
        atomicAdd(&stats[row * 4 + 3], SLG[s]);
      }
  }
}

// Per-row nonlinearity + final scalar. Single block.
__global__ void combine_k(const float* __restrict__ stats,
                          const double* __restrict__ acc,
                          float* __restrict__ out)
{
  double part = 0.0;
  for (int r = threadIdx.x; r < NROWS; r += 256) {
    float S   = stats[r * 4 + 0];
    float n   = stats[r * 4 + 1];   // exact: integer-valued sums < 2^24
    float SYL = stats[r * 4 + 2];
    float SLG = stats[r * 4 + 3];
    part += (double)lgammaf(n + 1.0f) - (double)SLG + (double)SYL
          - (double)n * (double)logf(S);
  }
  part = wredd(part);
  __shared__ double pd[4];
  if ((threadIdx.x & 63) == 0) pd[threadIdx.x >> 6] = part;
  __syncthreads();
  if (threadIdx.x == 0) {
    out[0] = (float)(pd[0] + pd[1] + pd[2] + pd[3] + acc[0]);
  }
}

extern "C" void kernel_launch(void* const* d_in, const int* in_sizes, int n_in,
                              void* d_out, int out_size, void* d_ws, size_t ws_size,
                              hipStream_t stream) {
  const float* X    = (const float*)d_in[0];
  const int*   Y    = (const int*)d_in[1];
  const float* mu   = (const float*)d_in[2];
  const float* beta = (const float*)d_in[3];
  const float* m0   = (const float*)d_in[4];
  const float* s0   = (const float*)d_in[5];
  float* out = (float*)d_out;

  float*  stats = (float*)d_ws;
  double* acc   = (double*)((char*)d_ws + STATS_N * sizeof(float));

  init_ws_k<<<dim3((STATS_N + 255) / 256), dim3(256), 0, stream>>>(stats, acc);
  mainprior_k<<<dim3(MAINB + PRIORB), dim3(256), 0, stream>>>(
      X, Y, mu, beta, m0, s0, stats, acc);
  combine_k<<<dim3(1), dim3(256), 0, stream>>>(stats, acc, out);
}

// Round 3
// 79.443 us; speedup vs baseline: 1.4797x; 1.4797x over previous
//
#include <hip/hip_runtime.h>
#include <math.h>

#define NROWS 2048
#define KDIM  20000
#define PDIM  32
#define NTILE 1250            // 20000 / 16 column tiles
#define CCH   64              // column chunks
#define RG    32              // row groups of 64 samples (2048/64)
#define MAINB (RG * CCH)      // 2048 main blocks = 8 per CU
#define PRIORB 64
#define STATS_N (NROWS * 4)

typedef short bf16x8 __attribute__((ext_vector_type(8)));
typedef float f32x4  __attribute__((ext_vector_type(4)));

__device__ __forceinline__ short f2bf(float f) {
  unsigned u = __float_as_uint(f);
  u += 0x7FFF + ((u >> 16) & 1);          // RNE
  return (short)(u >> 16);
}

__device__ __forceinline__ float wredf(float v) {
#pragma unroll
  for (int o = 32; o > 0; o >>= 1) v += __shfl_down(v, o, 64);
  return v;
}
__device__ __forceinline__ double wredd(double v) {
#pragma unroll
  for (int o = 32; o > 0; o >>= 1) v += __shfl_down(v, o, 64);
  return v;
}

__global__ void init_ws_k(float* stats, double* acc) {
  int i = blockIdx.x * blockDim.x + threadIdx.x;
  if (i < STATS_N) stats[i] = 0.0f;
  if (i == 0) acc[0] = 0.0;
}

// blocks [0, MAINB): transposed-MFMA logits + fused multinomial stats.
//   Per wave: 16 samples. D[i][j] = logit[sample j][col0+i]; lane (lg,ln)
//   holds cols lg*4+0..3 of sample ln -> Y is ONE int4 per lane per tile.
// blocks [MAINB, +PRIORB): Gaussian prior term.
__global__ __launch_bounds__(256, 8) void mainprior_k(
    const float* __restrict__ X, const int* __restrict__ Y,
    const float* __restrict__ mu, const float* __restrict__ beta,
    const float* __restrict__ m0p, const float* __restrict__ s0p,
    float* __restrict__ stats, double* __restrict__ acc)
{
  __shared__ float lgt[128];
  __shared__ float red[4];
  const int tid = threadIdx.x;

  if (blockIdx.x >= MAINB) {
    // ---------------- prior blocks ----------------
    const int b = blockIdx.x - MAINB;
    const float m0 = m0p[0], s0 = s0p[0];
    const float inv2s2 = 0.5f / (s0 * s0);
    const float cnst = -0.5f * logf(6.283185307179586f * s0 * s0);
    const int total = KDIM + PDIM * KDIM;
    float fs = 0.0f;
    for (int i = b * 256 + tid; i < total; i += PRIORB * 256) {
      float v = (i < KDIM) ? mu[i] : beta[i - KDIM];
      float d = v - m0;
      fs += cnst - d * d * inv2s2;
    }
    fs = wredf(fs);
    if ((tid & 63) == 0) red[tid >> 6] = fs;
    __syncthreads();
    if (tid == 0) {
      double tsum = (double)red[0] + (double)red[1] + (double)red[2] + (double)red[3];
      atomicAdd(acc, tsum);
    }
    return;
  }

  // ---------------- main blocks ----------------
  const int brow  = blockIdx.x / CCH;    // 0..31
  const int chunk = blockIdx.x % CCH;    // 0..63
  const int wave = tid >> 6;
  const int lane = tid & 63;
  const int lg = lane >> 4;              // lane group 0..3
  const int ln = lane & 15;              // lane within group
  const int sample = brow * 64 + wave * 16 + ln;   // this lane's sample

  if (tid < 128) lgt[tid] = lgammaf((float)tid + 1.0f);
  __syncthreads();

  // B operand: X[sample][k], k = lg*8 + i  (col = ln, k = lg*8+i layout)
  bf16x8 xb;
  {
    const float* xp = X + sample * PDIM + lg * 8;
    float4 x0 = *(const float4*)xp;
    float4 x1 = *(const float4*)(xp + 4);
    xb[0] = f2bf(x0.x); xb[1] = f2bf(x0.y); xb[2] = f2bf(x0.z); xb[3] = f2bf(x0.w);
    xb[4] = f2bf(x1.x); xb[5] = f2bf(x1.y); xb[6] = f2bf(x1.z); xb[7] = f2bf(x1.w);
  }

  const size_t ybase = (size_t)sample * KDIM + (size_t)lg * 4;
  const float* bcol = beta + lg * 8 * KDIM + ln;   // A: beta[k][col0+ln], k=lg*8+i

  float S = 0.f, SY = 0.f, SYL = 0.f, SLG = 0.f;

  int t = chunk;
  int4   yv = *(const int4*)(Y + ybase + (size_t)t * 16);
  float4 m4 = *(const float4*)(mu + t * 16 + lg * 4);

  while (t < NTILE) {
    const int col0 = t * 16;
    const int tn = t + CCH;
    const int ts = (tn < NTILE) ? tn : t;
    // prefetch next tile's Y (HBM) + mu while computing current
    int4   yv_n = *(const int4*)(Y + ybase + (size_t)ts * 16);
    float4 m4_n = *(const float4*)(mu + ts * 16 + lg * 4);

    // A operand: beta columns (L2-resident)
    bf16x8 af;
#pragma unroll
    for (int i = 0; i < 8; ++i) af[i] = f2bf(bcol[i * KDIM + col0]);

    f32x4 c = { m4.x, m4.y, m4.z, m4.w };   // mu folded into C-init
    c = __builtin_amdgcn_mfma_f32_16x16x32_bf16(af, xb, c, 0, 0, 0);

    const int ya[4] = { yv.x, yv.y, yv.z, yv.w };
#pragma unroll
    for (int j = 0; j < 4; ++j) {
      const float logit = c[j];
      S += __expf(logit);
      const float yf = (float)ya[j];
      SY  += yf;
      SYL += yf * logit;
      SLG += lgt[ya[j]];
    }
    t = tn; yv = yv_n; m4 = m4_n;
  }

  // reduce over the 4 lane-groups (lanes ^16, ^32 share the same sample)
  S   += __shfl_xor(S,   16, 64); S   += __shfl_xor(S,   32, 64);
  SY  += __shfl_xor(SY,  16, 64); SY  += __shfl_xor(SY,  32, 64);
  SYL += __shfl_xor(SYL, 16, 64); SYL += __shfl_xor(SYL, 32, 64);
  SLG += __shfl_xor(SLG, 16, 64); SLG += __shfl_xor(SLG, 32, 64);

  if (lg == 0) {
    atomicAdd(&stats[sample * 4 + 0], S);
    atomicAdd(&stats[sample * 4 + 1], SY);
    atomicAdd(&stats[sample * 4 + 2], SYL);
    atomicAdd(&stats[sample * 4 + 3], SLG);
  }
}

// Per-row nonlinearity + final scalar. Single block.
__global__ void combine_k(const float* __restrict__ stats,
                          const double* __restrict__ acc,
                          float* __restrict__ out)
{
  double part = 0.0;
  for (int r = threadIdx.x; r < NROWS; r += 256) {
    float S   = stats[r * 4 + 0];
    float n   = stats[r * 4 + 1];   // exact: integer-valued sums < 2^24
    float SYL = stats[r * 4 + 2];
    float SLG = stats[r * 4 + 3];
    part += (double)lgammaf(n + 1.0f) - (double)SLG + (double)SYL
          - (double)n * (double)logf(S);
  }
  part = wredd(part);
  __shared__ double pd[4];
  if ((threadIdx.x & 63) == 0) pd[threadIdx.x >> 6] = part;
  __syncthreads();
  if (threadIdx.x == 0) {
    out[0] = (float)(pd[0] + pd[1] + pd[2] + pd[3] + acc[0]);
  }
}

extern "C" void kernel_launch(void* const* d_in, const int* in_sizes, int n_in,
                              void* d_out, int out_size, void* d_ws, size_t ws_size,
                              hipStream_t stream) {
  const float* X    = (const float*)d_in[0];
  const int*   Y    = (const int*)d_in[1];
  const float* mu   = (const float*)d_in[2];
  const float* beta = (const float*)d_in[3];
  const float* m0   = (const float*)d_in[4];
  const float* s0   = (const float*)d_in[5];
  float* out = (float*)d_out;

  float*  stats = (float*)d_ws;
  double* acc   = (double*)((char*)d_ws + STATS_N * sizeof(float));

  init_ws_k<<<dim3((STATS_N + 255) / 256), dim3(256), 0, stream>>>(stats, acc);
  mainprior_k<<<dim3(MAINB + PRIORB), dim3(256), 0, stream>>>(
      X, Y, mu, beta, m0, s0, stats, acc);
  combine_k<<<dim3(1), dim3(256), 0, stream>>>(stats, acc, out);
}

// Round 4
// 69.681 us; speedup vs baseline: 1.6870x; 1.1401x over previous
//
#include <hip/hip_runtime.h>
#include <math.h>

#define NROWS 2048
#define KDIM  20000
#define PDIM  32
#define NTILE 1250            // 20000 / 16 column tiles
#define CCH   64              // column chunks
#define RG    8               // row groups of 256 samples
#define MAINB (RG * CCH)      // 512 main blocks (2 per CU)
#define PREPB 79              // ceil(KDIM / 256)
#define PRIORB 64
#define STATS_N (NROWS * 4)

// fancy-path ws layout (bytes)
#define OFF_STATS (KDIM * PDIM * 2)            // betaT: 1,280,000
#define OFF_PRIOR (OFF_STATS + STATS_N * 4)    // stats: +32,768
#define WS_NEEDED (OFF_PRIOR + PREPB * 8)

typedef short bf16x8 __attribute__((ext_vector_type(8)));
typedef unsigned short u16x8 __attribute__((ext_vector_type(8)));
typedef float f32x4  __attribute__((ext_vector_type(4)));

__device__ __forceinline__ short f2bf(float f) {
  unsigned u = __float_as_uint(f);
  u += 0x7FFF + ((u >> 16) & 1);          // RNE
  return (short)(u >> 16);
}
__device__ __forceinline__ float wredf(float v) {
#pragma unroll
  for (int o = 32; o > 0; o >>= 1) v += __shfl_down(v, o, 64);
  return v;
}
__device__ __forceinline__ double wredd(double v) {
#pragma unroll
  for (int o = 32; o > 0; o >>= 1) v += __shfl_down(v, o, 64);
  return v;
}

// ===================== fancy path =====================

// betaT[k][p] bf16 transpose + Gaussian prior partials + stats zeroing.
__global__ void prep_k(const float* __restrict__ beta, const float* __restrict__ mu,
                       const float* __restrict__ m0p, const float* __restrict__ s0p,
                       unsigned short* __restrict__ betaT,
                       float* __restrict__ stats, double* __restrict__ priorpart)
{
  __shared__ float red[4];
  const int tid = threadIdx.x;
  const int gi = blockIdx.x * 256 + tid;
  if (gi < STATS_N) stats[gi] = 0.0f;

  const float m0 = m0p[0], s0 = s0p[0];
  const float inv2s2 = 0.5f / (s0 * s0);
  const float cnst = -0.5f * logf(6.283185307179586f * s0 * s0);
  const int k = gi;
  float fs = 0.0f;
  if (k < KDIM) {
    float d = mu[k] - m0;
    fs += cnst - d * d * inv2s2;
    unsigned short loc[PDIM];
#pragma unroll
    for (int p = 0; p < PDIM; ++p) {
      float v = beta[p * KDIM + k];
      float dd = v - m0;
      fs += cnst - dd * dd * inv2s2;
      loc[p] = (unsigned short)f2bf(v);
    }
#pragma unroll
    for (int q = 0; q < 4; ++q) {
      u16x8 w;
#pragma unroll
      for (int i = 0; i < 8; ++i) w[i] = loc[q * 8 + i];
      *(u16x8*)(betaT + k * PDIM + q * 8) = w;
    }
  }
  fs = wredf(fs);
  if ((tid & 63) == 0) red[tid >> 6] = fs;
  __syncthreads();
  if (tid == 0)
    priorpart[blockIdx.x] =
        (double)red[0] + (double)red[1] + (double)red[2] + (double)red[3];
}

// Main: wave owns 64 samples (4 MFMA fragments); per tile-iter only 6 vmem
// insts: 4x Y int4 + 1x betaT dwordx4 + 1x mu float4.
__global__ __launch_bounds__(256, 4) void main_k(
    const float* __restrict__ X, const int* __restrict__ Y,
    const float* __restrict__ mu, const unsigned short* __restrict__ betaT,
    float* __restrict__ stats)
{
  __shared__ float lgt[128];
  const int tid = threadIdx.x;
  if (tid < 128) lgt[tid] = lgammaf((float)tid + 1.0f);
  __syncthreads();

  const int brow  = blockIdx.x >> 6;     // / CCH
  const int chunk = blockIdx.x & (CCH - 1);
  const int wave = tid >> 6;
  const int lane = tid & 63;
  const int lg = lane >> 4;
  const int ln = lane & 15;
  const int sbase = brow * 256 + wave * 64;

  // B operands: X rows as bf16, persistent. Fragment F = samples sbase+F*16+ln.
  bf16x8 xb[4];
  int yoff[4];
#pragma unroll
  for (int F = 0; F < 4; ++F) {
    const int s = sbase + F * 16 + ln;
    const float* xp = X + s * PDIM + lg * 8;
    float4 x0 = *(const float4*)xp;
    float4 x1 = *(const float4*)(xp + 4);
    xb[F][0] = f2bf(x0.x); xb[F][1] = f2bf(x0.y);
    xb[F][2] = f2bf(x0.z); xb[F][3] = f2bf(x0.w);
    xb[F][4] = f2bf(x1.x); xb[F][5] = f2bf(x1.y);
    xb[F][6] = f2bf(x1.z); xb[F][7] = f2bf(x1.w);
    yoff[F] = s * KDIM + lg * 4;
  }

  float S[4], SY[4], SYL[4], SLG[4];
#pragma unroll
  for (int F = 0; F < 4; ++F) { S[F] = 0.f; SY[F] = 0.f; SYL[F] = 0.f; SLG[F] = 0.f; }

  // A operand source: betaT[(col0+ln)*32 + lg*8 .. +8] — one 16B load
  const unsigned short* bt = betaT + ln * PDIM + lg * 8;

  int t = chunk;
  bf16x8 af = *(const bf16x8*)(bt + t * 16 * PDIM);
  float4 m4 = *(const float4*)(mu + t * 16 + lg * 4);
  int4 yv[4];
#pragma unroll
  for (int F = 0; F < 4; ++F) yv[F] = *(const int4*)(Y + yoff[F] + t * 16);

  while (t < NTILE) {
    const int tn = t + CCH;
    const int ts = (tn < NTILE) ? tn : t;
    // prefetch next tile
    int4 yn[4];
#pragma unroll
    for (int F = 0; F < 4; ++F) yn[F] = *(const int4*)(Y + yoff[F] + ts * 16);
    bf16x8 afn = *(const bf16x8*)(bt + ts * 16 * PDIM);
    float4 mn  = *(const float4*)(mu + ts * 16 + lg * 4);

#pragma unroll
    for (int F = 0; F < 4; ++F) {
      f32x4 c = { m4.x, m4.y, m4.z, m4.w };
      c = __builtin_amdgcn_mfma_f32_16x16x32_bf16(af, xb[F], c, 0, 0, 0);
      const int ya[4] = { yv[F].x, yv[F].y, yv[F].z, yv[F].w };
#pragma unroll
      for (int j = 0; j < 4; ++j) {
        const float logit = c[j];
        S[F] += __expf(logit);
        const float yf = (float)ya[j];
        SY[F]  += yf;
        SYL[F] = fmaf(yf, logit, SYL[F]);
        SLG[F] += lgt[ya[j]];
      }
    }
    t = tn; af = afn; m4 = mn;
#pragma unroll
    for (int F = 0; F < 4; ++F) yv[F] = yn[F];
  }

#pragma unroll
  for (int F = 0; F < 4; ++F) {
    S[F]   += __shfl_xor(S[F],   16, 64); S[F]   += __shfl_xor(S[F],   32, 64);
    SY[F]  += __shfl_xor(SY[F],  16, 64); SY[F]  += __shfl_xor(SY[F],  32, 64);
    SYL[F] += __shfl_xor(SYL[F], 16, 64); SYL[F] += __shfl_xor(SYL[F], 32, 64);
    SLG[F] += __shfl_xor(SLG[F], 16, 64); SLG[F] += __shfl_xor(SLG[F], 32, 64);
  }
  if (lg == 0) {
#pragma unroll
    for (int F = 0; F < 4; ++F) {
      const int s = sbase + F * 16 + ln;
      atomicAdd(&stats[s * 4 + 0], S[F]);
      atomicAdd(&stats[s * 4 + 1], SY[F]);
      atomicAdd(&stats[s * 4 + 2], SYL[F]);
      atomicAdd(&stats[s * 4 + 3], SLG[F]);
    }
  }
}

__global__ void combine_k(const float* __restrict__ stats,
                          const double* __restrict__ priorpart,
                          float* __restrict__ out)
{
  double part = 0.0;
  for (int r = threadIdx.x; r < NROWS; r += 256) {
    float S   = stats[r * 4 + 0];
    float n   = stats[r * 4 + 1];
    float SYL = stats[r * 4 + 2];
    float SLG = stats[r * 4 + 3];
    part += (double)lgammaf(n + 1.0f) - (double)SLG + (double)SYL
          - (double)n * (double)logf(S);
  }
  for (int i = threadIdx.x; i < PREPB; i += 256) part += priorpart[i];
  part = wredd(part);
  __shared__ double pd[4];
  if ((threadIdx.x & 63) == 0) pd[threadIdx.x >> 6] = part;
  __syncthreads();
  if (threadIdx.x == 0)
    out[0] = (float)(pd[0] + pd[1] + pd[2] + pd[3]);
}

// ===================== fallback path (R3, needs only 32KB ws) =====================

__global__ void fb_init_k(float* stats, double* acc) {
  int i = blockIdx.x * blockDim.x + threadIdx.x;
  if (i < STATS_N) stats[i] = 0.0f;
  if (i == 0) acc[0] = 0.0;
}

__global__ __launch_bounds__(256, 8) void fb_main_k(
    const float* __restrict__ X, const int* __restrict__ Y,
    const float* __restrict__ mu, const float* __restrict__ beta,
    const float* __restrict__ m0p, const float* __restrict__ s0p,
    float* __restrict__ stats, double* __restrict__ acc)
{
  __shared__ float lgt[128];
  __shared__ float red[4];
  const int tid = threadIdx.x;
  const int FB_MAINB = 2048;

  if (blockIdx.x >= FB_MAINB) {
    const int b = blockIdx.x - FB_MAINB;
    const float m0 = m0p[0], s0 = s0p[0];
    const float inv2s2 = 0.5f / (s0 * s0);
    const float cnst = -0.5f * logf(6.283185307179586f * s0 * s0);
    const int total = KDIM + PDIM * KDIM;
    float fs = 0.0f;
    for (int i = b * 256 + tid; i < total; i += PRIORB * 256) {
      float v = (i < KDIM) ? mu[i] : beta[i - KDIM];
      float d = v - m0;
      fs += cnst - d * d * inv2s2;
    }
    fs = wredf(fs);
    if ((tid & 63) == 0) red[tid >> 6] = fs;
    __syncthreads();
    if (tid == 0) {
      double tsum = (double)red[0] + (double)red[1] + (double)red[2] + (double)red[3];
      atomicAdd(acc, tsum);
    }
    return;
  }

  const int brow  = blockIdx.x / 64;
  const int chunk = blockIdx.x % 64;
  const int wave = tid >> 6;
  const int lane = tid & 63;
  const int lg = lane >> 4;
  const int ln = lane & 15;
  const int sample = brow * 64 + wave * 16 + ln;

  if (tid < 128) lgt[tid] = lgammaf((float)tid + 1.0f);
  __syncthreads();

  bf16x8 xb;
  {
    const float* xp = X + sample * PDIM + lg * 8;
    float4 x0 = *(const float4*)xp;
    float4 x1 = *(const float4*)(xp + 4);
    xb[0] = f2bf(x0.x); xb[1] = f2bf(x0.y); xb[2] = f2bf(x0.z); xb[3] = f2bf(x0.w);
    xb[4] = f2bf(x1.x); xb[5] = f2bf(x1.y); xb[6] = f2bf(x1.z); xb[7] = f2bf(x1.w);
  }
  const size_t ybase = (size_t)sample * KDIM + (size_t)lg * 4;
  const float* bcol = beta + lg * 8 * KDIM + ln;

  float S = 0.f, SY = 0.f, SYL = 0.f, SLG = 0.f;
  int t = chunk;
  int4   yv = *(const int4*)(Y + ybase + (size_t)t * 16);
  float4 m4 = *(const float4*)(mu + t * 16 + lg * 4);

  while (t < NTILE) {
    const int col0 = t * 16;
    const int tn = t + 64;
    const int ts = (tn < NTILE) ? tn : t;
    int4   yv_n = *(const int4*)(Y + ybase + (size_t)ts * 16);
    float4 m4_n = *(const float4*)(mu + ts * 16 + lg * 4);
    bf16x8 af;
#pragma unroll
    for (int i = 0; i < 8; ++i) af[i] = f2bf(bcol[i * KDIM + col0]);
    f32x4 c = { m4.x, m4.y, m4.z, m4.w };
    c = __builtin_amdgcn_mfma_f32_16x16x32_bf16(af, xb, c, 0, 0, 0);
    const int ya[4] = { yv.x, yv.y, yv.z, yv.w };
#pragma unroll
    for (int j = 0; j < 4; ++j) {
      const float logit = c[j];
      S += __expf(logit);
      const float yf = (float)ya[j];
      SY  += yf;
      SYL += yf * logit;
      SLG += lgt[ya[j]];
    }
    t = tn; yv = yv_n; m4 = m4_n;
  }

  S   += __shfl_xor(S,   16, 64); S   += __shfl_xor(S,   32, 64);
  SY  += __shfl_xor(SY,  16, 64); SY  += __shfl_xor(SY,  32, 64);
  SYL += __shfl_xor(SYL, 16, 64); SYL += __shfl_xor(SYL, 32, 64);
  SLG += __shfl_xor(SLG, 16, 64); SLG += __shfl_xor(SLG, 32, 64);
  if (lg == 0) {
    atomicAdd(&stats[sample * 4 + 0], S);
    atomicAdd(&stats[sample * 4 + 1], SY);
    atomicAdd(&stats[sample * 4 + 2], SYL);
    atomicAdd(&stats[sample * 4 + 3], SLG);
  }
}

__global__ void fb_combine_k(const float* __restrict__ stats,
                             const double* __restrict__ acc,
                             float* __restrict__ out)
{
  double part = 0.0;
  for (int r = threadIdx.x; r < NROWS; r += 256) {
    float S   = stats[r * 4 + 0];
    float n   = stats[r * 4 + 1];
    float SYL = stats[r * 4 + 2];
    float SLG = stats[r * 4 + 3];
    part += (double)lgammaf(n + 1.0f) - (double)SLG + (double)SYL
          - (double)n * (double)logf(S);
  }
  part = wredd(part);
  __shared__ double pd[4];
  if ((threadIdx.x & 63) == 0) pd[threadIdx.x >> 6] = part;
  __syncthreads();
  if (threadIdx.x == 0)
    out[0] = (float)(pd[0] + pd[1] + pd[2] + pd[3] + acc[0]);
}

extern "C" void kernel_launch(void* const* d_in, const int* in_sizes, int n_in,
                              void* d_out, int out_size, void* d_ws, size_t ws_size,
                              hipStream_t stream) {
  const float* X    = (const float*)d_in[0];
  const int*   Y    = (const int*)d_in[1];
  const float* mu   = (const float*)d_in[2];
  const float* beta = (const float*)d_in[3];
  const float* m0   = (const float*)d_in[4];
  const float* s0   = (const float*)d_in[5];
  float* out = (float*)d_out;

  if (ws_size >= (size_t)WS_NEEDED) {
    unsigned short* betaT = (unsigned short*)d_ws;
    float*  stats = (float*)((char*)d_ws + OFF_STATS);
    double* prior = (double*)((char*)d_ws + OFF_PRIOR);
    prep_k<<<dim3(PREPB), dim3(256), 0, stream>>>(beta, mu, m0, s0, betaT, stats, prior);
    main_k<<<dim3(MAINB), dim3(256), 0, stream>>>(X, Y, mu, betaT, stats);
    combine_k<<<dim3(1), dim3(256), 0, stream>>>(stats, prior, out);
  } else {
    float*  stats = (float*)d_ws;
    double* acc   = (double*)((char*)d_ws + STATS_N * sizeof(float));
    fb_init_k<<<dim3((STATS_N + 255) / 256), dim3(256), 0, stream>>>(stats, acc);
    fb_main_k<<<dim3(2048 + PRIORB), dim3(256), 0, stream>>>(
        X, Y, mu, beta, m0, s0, stats, acc);
    fb_combine_k<<<dim3(1), dim3(256), 0, stream>>>(stats, acc, out);
  }
}